// Round 1
// baseline (109779.993 us; speedup 1.0000x reference)
//
#include <hip/hip_runtime.h>

#define T_STEPS 4096
#define HID 512
#define NLAYER 3
#define WGS_PER_LAYER 32
#define NWG (NLAYER * WGS_PER_LAYER)
#define NTHREADS 512
#define HCHUNK 16
#define S_TOTAL (T_STEPS + NLAYER - 1)
#define HSEQ_ELEMS ((T_STEPS + 1) * HID)
#define HEAD_BLOCKS 256

__device__ __forceinline__ float sigmoid_fast(float x) {
    return 1.0f / (1.0f + __expf(-x));
}
__device__ __forceinline__ float tanh_fast(float x) {
    // tanh(x) = 2*sigmoid(2x) - 1 ; correct limits at +/-inf via __expf saturation
    return 2.0f / (1.0f + __expf(-2.0f * x)) - 1.0f;
}
// XOR-swizzle on element index: spreads 128B-strided ds_read_b128 across banks (G4).
__device__ __forceinline__ int swz(int e) { return e ^ (((e >> 5) & 7) << 2); }

// Persistent systolic 3-layer LSTM scan. 96 WGs: WG = layer*32 + w.
// Layer l at global step s computes timestep t = s - l.
// v = concat(x_part[512], h_prev[512]) in LDS; weights stationary in VGPRs.
__global__ void __launch_bounds__(NTHREADS, 2)
lstm_scan(const float* __restrict__ x,
          const float* __restrict__ Wih0, const float* __restrict__ Whh0,
          const float* __restrict__ bih0, const float* __restrict__ bhh0,
          const float* __restrict__ Wih1, const float* __restrict__ Whh1,
          const float* __restrict__ bih1, const float* __restrict__ bhh1,
          const float* __restrict__ Wih2, const float* __restrict__ Whh2,
          const float* __restrict__ bih2, const float* __restrict__ bhh2,
          float* __restrict__ ws)
{
    const int wg    = blockIdx.x;
    const int layer = wg >> 5;
    const int w     = wg & 31;
    const int tid   = threadIdx.x;
    const int rg    = tid >> 5;   // row-group 0..15 (4 rows each)
    const int cg    = tid & 31;   // col-group 0..31 (32 cols each)

    int*   flags = (int*)ws;
    float* hseq0 = ws + 128;
    float* hseq1 = hseq0 + HSEQ_ELEMS;
    float* hseq2 = hseq1 + HSEQ_ELEMS;
    float* hown        = (layer == 0) ? hseq0 : ((layer == 1) ? hseq1 : hseq2);
    const float* hprev = (layer == 0) ? hseq0 : ((layer == 1) ? hseq0 : hseq1);

    const float* Wih = (layer == 0) ? Wih0 : ((layer == 1) ? Wih1 : Wih2);
    const float* Whh = (layer == 0) ? Whh0 : ((layer == 1) ? Whh1 : Whh2);
    const float* bih = (layer == 0) ? bih0 : ((layer == 1) ? bih1 : bih2);
    const float* bhh = (layer == 0) ? bhh0 : ((layer == 1) ? bhh1 : bhh2);

    __shared__ float v_lds[1024];
    __shared__ float g_lds[64];
    __shared__ float bias_lds[64];

    // ---- load stationary weights into registers: 4 rows x 32 cols ----
    float wr[4][32];
    #pragma unroll
    for (int r = 0; r < 4; ++r) {
        const int lr   = 4 * rg + r;                               // local row 0..63
        const int grow = ((lr >> 4) * HID) + w * HCHUNK + (lr & 15); // global gate row
        #pragma unroll
        for (int j = 0; j < 32; ++j) {
            const int col = cg * 32 + j;   // 0..1023 over [x_part | h_part]
            float val;
            if (col < HID) {
                if (layer == 0) val = (col < 40) ? Wih0[grow * 40 + col] : 0.0f;
                else            val = Wih[grow * HID + col];
            } else {
                val = Whh[grow * HID + (col - HID)];
            }
            wr[r][j] = val;
        }
    }
    if (tid < 64) {
        const int lr   = tid;
        const int grow = ((lr >> 4) * HID) + w * HCHUNK + (lr & 15);
        bias_lds[lr] = bih[grow] + bhh[grow];
    }

    float c_state = 0.0f;   // cell state, meaningful for tid < 16

    for (int s = 0; s < S_TOTAL; ++s) {
        const int  t      = s - layer;
        const bool active = (t >= 0) && (t < T_STEPS);

        // ---- barrier: wait until all 96 WGs have finished step s-1 ----
        if (s > 0) {
            if (tid < 64) {
                const int i1 = tid;
                const int i2 = (tid < 32) ? (64 + tid) : tid;
                while (1) {
                    int f1 = __hip_atomic_load(&flags[i1], __ATOMIC_RELAXED, __HIP_MEMORY_SCOPE_AGENT);
                    int f2 = __hip_atomic_load(&flags[i2], __ATOMIC_RELAXED, __HIP_MEMORY_SCOPE_AGENT);
                    if (__all(f1 >= s && f2 >= s)) break;
                    __builtin_amdgcn_s_sleep(1);
                }
            }
        }
        __syncthreads();
        __threadfence();   // acquire side: order subsequent data loads after flag observation

        // ---- stage v = [x_part | h_prev] into LDS (swizzled) ----
        if (active) {
            float xv, hv;
            if (layer == 0) {
                xv = (tid < 40) ? x[t * 40 + tid] : 0.0f;
            } else {
                xv = __hip_atomic_load(&hprev[(t + 1) * HID + tid], __ATOMIC_RELAXED, __HIP_MEMORY_SCOPE_AGENT);
            }
            hv = __hip_atomic_load(&hown[t * HID + tid], __ATOMIC_RELAXED, __HIP_MEMORY_SCOPE_AGENT);
            v_lds[swz(tid)]       = xv;
            v_lds[swz(HID + tid)] = hv;
        }
        __syncthreads();

        // ---- matvec: each thread 4 rows x 32 cols from registers ----
        if (active) {
            float acc0 = 0.f, acc1 = 0.f, acc2 = 0.f, acc3 = 0.f;
            #pragma unroll
            for (int j = 0; j < 8; ++j) {
                const int e = (cg * 32 + j * 4) ^ ((cg & 7) << 2);
                const float4 hv4 = *reinterpret_cast<const float4*>(&v_lds[e]);
                acc0 = fmaf(wr[0][4 * j + 0], hv4.x, acc0);
                acc0 = fmaf(wr[0][4 * j + 1], hv4.y, acc0);
                acc0 = fmaf(wr[0][4 * j + 2], hv4.z, acc0);
                acc0 = fmaf(wr[0][4 * j + 3], hv4.w, acc0);
                acc1 = fmaf(wr[1][4 * j + 0], hv4.x, acc1);
                acc1 = fmaf(wr[1][4 * j + 1], hv4.y, acc1);
                acc1 = fmaf(wr[1][4 * j + 2], hv4.z, acc1);
                acc1 = fmaf(wr[1][4 * j + 3], hv4.w, acc1);
                acc2 = fmaf(wr[2][4 * j + 0], hv4.x, acc2);
                acc2 = fmaf(wr[2][4 * j + 1], hv4.y, acc2);
                acc2 = fmaf(wr[2][4 * j + 2], hv4.z, acc2);
                acc2 = fmaf(wr[2][4 * j + 3], hv4.w, acc2);
                acc3 = fmaf(wr[3][4 * j + 0], hv4.x, acc3);
                acc3 = fmaf(wr[3][4 * j + 1], hv4.y, acc3);
                acc3 = fmaf(wr[3][4 * j + 2], hv4.z, acc3);
                acc3 = fmaf(wr[3][4 * j + 3], hv4.w, acc3);
            }
            // butterfly reduce across the 32 col-groups (lanes cg, same rg)
            #pragma unroll
            for (int m = 1; m < 32; m <<= 1) {
                acc0 += __shfl_xor(acc0, m, 64);
                acc1 += __shfl_xor(acc1, m, 64);
                acc2 += __shfl_xor(acc2, m, 64);
                acc3 += __shfl_xor(acc3, m, 64);
            }
            if (cg == 0) {
                g_lds[4 * rg + 0] = acc0;
                g_lds[4 * rg + 1] = acc1;
                g_lds[4 * rg + 2] = acc2;
                g_lds[4 * rg + 3] = acc3;
            }
        }
        __syncthreads();

        // ---- gates, state update, publish h chunk ----
        if (active && tid < HCHUNK) {
            const float gi = sigmoid_fast(g_lds[tid]      + bias_lds[tid]);
            const float gf = sigmoid_fast(g_lds[16 + tid] + bias_lds[16 + tid]);
            const float gc = tanh_fast   (g_lds[32 + tid] + bias_lds[32 + tid]);
            const float go = sigmoid_fast(g_lds[48 + tid] + bias_lds[48 + tid]);
            c_state = gf * c_state + gi * gc;
            const float h = go * tanh_fast(c_state);
            __hip_atomic_store(&hown[(t + 1) * HID + w * HCHUNK + tid], h,
                               __ATOMIC_RELAXED, __HIP_MEMORY_SCOPE_AGENT);
        }
        __threadfence();      // release side: make h stores agent-visible
        __syncthreads();
        if (tid == 0) {
            __hip_atomic_store(&flags[wg], s + 1, __ATOMIC_RELEASE, __HIP_MEMORY_SCOPE_AGENT);
        }
    }
}

// Head: out[t] = softmax( tanh(h2[t] @ W1^T + b1) @ W2^T + b2 )
__global__ void __launch_bounds__(256)
head_kernel(const float* __restrict__ ws_ro,
            const float* __restrict__ W1, const float* __restrict__ b1,
            const float* __restrict__ W2, const float* __restrict__ b2,
            float* __restrict__ out)
{
    __shared__ float w1_lds[26 * 516];   // padded stride to break bank conflicts
    __shared__ float b1_lds[26];
    __shared__ float w2_lds[52];
    __shared__ float g_lds[32];
    const int tid = threadIdx.x;

    for (int i = tid; i < 26 * 512; i += 256)
        w1_lds[(i >> 9) * 516 + (i & 511)] = W1[i];
    if (tid < 26) b1_lds[tid] = b1[tid];
    if (tid < 52) w2_lds[tid] = W2[tid];
    __syncthreads();

    const float* h2 = ws_ro + 128 + 2 * HSEQ_ELEMS;   // layer-2 h sequence base
    const int r = tid >> 3;   // 0..31 (rows 0..25 used)
    const int c = tid & 7;    // 8 chunks of 64

    for (int t = blockIdx.x; t < T_STEPS; t += HEAD_BLOCKS) {
        float acc = 0.0f;
        if (r < 26) {
            const float* hrow = h2 + (t + 1) * HID + c * 64;
            const float* wrow = &w1_lds[r * 516 + c * 64];
            #pragma unroll
            for (int k = 0; k < 64; k += 4) {
                const float4 hv = *reinterpret_cast<const float4*>(&hrow[k]);
                const float4 wv = *reinterpret_cast<const float4*>(&wrow[k]);
                acc += hv.x * wv.x + hv.y * wv.y + hv.z * wv.z + hv.w * wv.w;
            }
        }
        acc += __shfl_xor(acc, 1, 64);
        acc += __shfl_xor(acc, 2, 64);
        acc += __shfl_xor(acc, 4, 64);
        if (r < 26 && c == 0) g_lds[r] = acc;
        __syncthreads();
        if (tid == 0) {
            float l0 = b2[0], l1 = b2[1];
            for (int j = 0; j < 26; ++j) {
                const float tj = tanhf(g_lds[j] + b1_lds[j]);
                l0 = fmaf(w2_lds[j],      tj, l0);
                l1 = fmaf(w2_lds[26 + j], tj, l1);
            }
            const float m  = fmaxf(l0, l1);
            const float e0 = __expf(l0 - m), e1 = __expf(l1 - m);
            const float inv = 1.0f / (e0 + e1);
            out[t * 2 + 0] = e0 * inv;
            out[t * 2 + 1] = e1 * inv;
        }
        __syncthreads();
    }
}

extern "C" void kernel_launch(void* const* d_in, const int* in_sizes, int n_in,
                              void* d_out, int out_size, void* d_ws, size_t ws_size,
                              hipStream_t stream)
{
    const float* x    = (const float*)d_in[0];
    const float* Wih0 = (const float*)d_in[1];
    const float* Whh0 = (const float*)d_in[2];
    const float* bih0 = (const float*)d_in[3];
    const float* bhh0 = (const float*)d_in[4];
    const float* Wih1 = (const float*)d_in[5];
    const float* Whh1 = (const float*)d_in[6];
    const float* bih1 = (const float*)d_in[7];
    const float* bhh1 = (const float*)d_in[8];
    const float* Wih2 = (const float*)d_in[9];
    const float* Whh2 = (const float*)d_in[10];
    const float* bih2 = (const float*)d_in[11];
    const float* bhh2 = (const float*)d_in[12];
    const float* W1   = (const float*)d_in[13];
    const float* b1   = (const float*)d_in[14];
    const float* W2   = (const float*)d_in[15];
    const float* b2   = (const float*)d_in[16];

    float* ws = (float*)d_ws;

    // ws layout (floats): [0..128) flags/pad ; then 3 x HSEQ_ELEMS h-sequences
    // (row 0 of each sequence = h_{-1} = 0). Total ~24 MB.
    hipMemsetAsync(d_ws, 0, 512, stream);                                              // flags
    hipMemsetAsync((char*)d_ws + 512, 0, HID * sizeof(float), stream);                 // h0 row0
    hipMemsetAsync((char*)d_ws + 512 + (size_t)HSEQ_ELEMS * 4, 0, HID * sizeof(float), stream);      // h1 row0
    hipMemsetAsync((char*)d_ws + 512 + (size_t)2 * HSEQ_ELEMS * 4, 0, HID * sizeof(float), stream);  // h2 row0

    lstm_scan<<<NWG, NTHREADS, 0, stream>>>(x,
        Wih0, Whh0, bih0, bhh0,
        Wih1, Whh1, bih1, bhh1,
        Wih2, Whh2, bih2, bhh2, ws);

    head_kernel<<<HEAD_BLOCKS, 256, 0, stream>>>(ws, W1, b1, W2, b2, (float*)d_out);
}

// Round 2
// 16120.195 us; speedup vs baseline: 6.8101x; 6.8101x over previous
//
#include <hip/hip_runtime.h>

#define T_STEPS 4096
#define HID 512
#define NLAYER 3
#define WGS_PER_LAYER 32
#define NWG (NLAYER * WGS_PER_LAYER)
#define NTHREADS 512
#define HCHUNK 16
#define S_TOTAL (T_STEPS + NLAYER - 1)
#define HSEQ_ELEMS ((T_STEPS + 1) * HID)
#define HEAD_BLOCKS 256

typedef float f32x16 __attribute__((ext_vector_type(16)));

__device__ __forceinline__ float sigmoid_fast(float x) {
    return 1.0f / (1.0f + __expf(-x));
}
__device__ __forceinline__ float tanh_fast(float x) {
    return 2.0f / (1.0f + __expf(-2.0f * x)) - 1.0f;
}
// XOR-swizzle on element index: spreads 128B-strided ds_read_b128 across banks (G4).
__device__ __forceinline__ int swz(int e) { return e ^ (((e >> 5) & 7) << 2); }

__device__ __forceinline__ float wload(int layer, const float* __restrict__ Wih,
                                       const float* __restrict__ Whh, int grow, int col) {
    if (col >= HID) return Whh[grow * HID + (col - HID)];
    if (layer == 0) return (col < 40) ? Wih[grow * 40 + col] : 0.0f;
    return Wih[grow * HID + col];
}

// Load 16 consecutive weight cols for local row r_, half h_ into named vector V.
// All vector subscripts are compile-time constants -> guaranteed VGPR residency.
#define LOADV(V, r_, h_) { \
    const int lr   = 4 * rg + (r_); \
    const int grow = ((lr >> 4) * HID) + w * HCHUNK + (lr & 15); \
    _Pragma("unroll") \
    for (int k = 0; k < 16; ++k) \
        V[k] = wload(layer, Wih, Whh, grow, cg * 32 + (h_) * 16 + k); }

#define STEP_J(jj, V0, V1, V2, V3, bb) { \
    const int e = (cg * 32 + (jj) * 4) ^ ((cg & 7) << 2); \
    const float4 hv4 = *reinterpret_cast<const float4*>(&v_lds[e]); \
    acc0 = fmaf(V0[(bb)+0], hv4.x, acc0); \
    acc0 = fmaf(V0[(bb)+1], hv4.y, acc0); \
    acc0 = fmaf(V0[(bb)+2], hv4.z, acc0); \
    acc0 = fmaf(V0[(bb)+3], hv4.w, acc0); \
    acc1 = fmaf(V1[(bb)+0], hv4.x, acc1); \
    acc1 = fmaf(V1[(bb)+1], hv4.y, acc1); \
    acc1 = fmaf(V1[(bb)+2], hv4.z, acc1); \
    acc1 = fmaf(V1[(bb)+3], hv4.w, acc1); \
    acc2 = fmaf(V2[(bb)+0], hv4.x, acc2); \
    acc2 = fmaf(V2[(bb)+1], hv4.y, acc2); \
    acc2 = fmaf(V2[(bb)+2], hv4.z, acc2); \
    acc2 = fmaf(V2[(bb)+3], hv4.w, acc2); \
    acc3 = fmaf(V3[(bb)+0], hv4.x, acc3); \
    acc3 = fmaf(V3[(bb)+1], hv4.y, acc3); \
    acc3 = fmaf(V3[(bb)+2], hv4.z, acc3); \
    acc3 = fmaf(V3[(bb)+3], hv4.w, acc3); }

// Persistent systolic 3-layer LSTM scan. 96 WGs: WG = layer*32 + w.
// Layer l at global step s computes timestep t = s - l.
// Weights stationary in VGPRs (128/thread); v = [x_part|h_prev] staged in LDS.
__global__ void __launch_bounds__(NTHREADS, 1)
lstm_scan(const float* __restrict__ x,
          const float* __restrict__ Wih0, const float* __restrict__ Whh0,
          const float* __restrict__ bih0, const float* __restrict__ bhh0,
          const float* __restrict__ Wih1, const float* __restrict__ Whh1,
          const float* __restrict__ bih1, const float* __restrict__ bhh1,
          const float* __restrict__ Wih2, const float* __restrict__ Whh2,
          const float* __restrict__ bih2, const float* __restrict__ bhh2,
          float* __restrict__ ws)
{
    const int wg    = blockIdx.x;
    const int layer = wg >> 5;
    const int w     = wg & 31;
    const int tid   = threadIdx.x;
    const int rg    = tid >> 5;   // row-group 0..15 (4 rows each)
    const int cg    = tid & 31;   // col-group 0..31 (32 cols each)

    int*   flags = (int*)ws;
    float* hseq0 = ws + 128;
    float* hseq1 = hseq0 + HSEQ_ELEMS;
    float* hseq2 = hseq1 + HSEQ_ELEMS;
    float* hown        = (layer == 0) ? hseq0 : ((layer == 1) ? hseq1 : hseq2);
    const float* hprev = (layer == 0) ? hseq0 : ((layer == 1) ? hseq0 : hseq1);

    const float* Wih = (layer == 0) ? Wih0 : ((layer == 1) ? Wih1 : Wih2);
    const float* Whh = (layer == 0) ? Whh0 : ((layer == 1) ? Whh1 : Whh2);
    const float* bih = (layer == 0) ? bih0 : ((layer == 1) ? bih1 : bih2);
    const float* bhh = (layer == 0) ? bhh0 : ((layer == 1) ? bhh1 : bhh2);

    __shared__ float v_lds[1024];
    __shared__ float g_lds[64];
    __shared__ float bias_lds[64];

    // ---- stationary weights: 4 rows x 32 cols per thread, in named vector regs ----
    f32x16 wv0, wv1, wv2, wv3, wv4, wv5, wv6, wv7;
    LOADV(wv0, 0, 0) LOADV(wv1, 0, 1)
    LOADV(wv2, 1, 0) LOADV(wv3, 1, 1)
    LOADV(wv4, 2, 0) LOADV(wv5, 2, 1)
    LOADV(wv6, 3, 0) LOADV(wv7, 3, 1)

    if (tid < 64) {
        const int lr   = tid;
        const int grow = ((lr >> 4) * HID) + w * HCHUNK + (lr & 15);
        bias_lds[lr] = bih[grow] + bhh[grow];
    }

    float c_state = 0.0f;   // cell state, meaningful for tid < 16

    for (int s = 0; s < S_TOTAL; ++s) {
        const int  t      = s - layer;
        const bool active = (t >= 0) && (t < T_STEPS);

        // ---- wait: layers {l-1, l} must have finished step s-1 (64 flags) ----
        if (s > 0) {
            if (tid < 64) {
                const int fidx = (layer == 0) ? (tid & 31) : ((layer - 1) * 32 + tid);
                while (1) {
                    const int f = __hip_atomic_load(&flags[fidx], __ATOMIC_RELAXED,
                                                    __HIP_MEMORY_SCOPE_AGENT);
                    if (__all(f >= s)) break;
                }
            }
            asm volatile("" ::: "memory");   // compiler barrier: no load hoisting above poll
        }
        __syncthreads();

        // ---- stage v = [x_part | h_prev] into LDS (swizzled) ----
        if (active) {
            float xv, hv;
            if (layer == 0) {
                xv = (tid < 40) ? x[t * 40 + tid] : 0.0f;
            } else {
                xv = __hip_atomic_load(&hprev[(t + 1) * HID + tid], __ATOMIC_RELAXED,
                                       __HIP_MEMORY_SCOPE_AGENT);
            }
            hv = __hip_atomic_load(&hown[t * HID + tid], __ATOMIC_RELAXED,
                                   __HIP_MEMORY_SCOPE_AGENT);
            v_lds[swz(tid)]       = xv;
            v_lds[swz(HID + tid)] = hv;
        }
        __syncthreads();

        // ---- matvec: 4 rows x 32 cols from registers ----
        if (active) {
            float acc0 = 0.f, acc1 = 0.f, acc2 = 0.f, acc3 = 0.f;
            STEP_J(0, wv0, wv2, wv4, wv6, 0)
            STEP_J(1, wv0, wv2, wv4, wv6, 4)
            STEP_J(2, wv0, wv2, wv4, wv6, 8)
            STEP_J(3, wv0, wv2, wv4, wv6, 12)
            STEP_J(4, wv1, wv3, wv5, wv7, 0)
            STEP_J(5, wv1, wv3, wv5, wv7, 4)
            STEP_J(6, wv1, wv3, wv5, wv7, 8)
            STEP_J(7, wv1, wv3, wv5, wv7, 12)
            #pragma unroll
            for (int m = 1; m < 32; m <<= 1) {
                acc0 += __shfl_xor(acc0, m, 64);
                acc1 += __shfl_xor(acc1, m, 64);
                acc2 += __shfl_xor(acc2, m, 64);
                acc3 += __shfl_xor(acc3, m, 64);
            }
            if (cg == 0) {
                g_lds[4 * rg + 0] = acc0;
                g_lds[4 * rg + 1] = acc1;
                g_lds[4 * rg + 2] = acc2;
                g_lds[4 * rg + 3] = acc3;
            }
        }
        __syncthreads();

        // ---- gates, state update, publish h chunk ----
        if (active && tid < HCHUNK) {
            const float gi = sigmoid_fast(g_lds[tid]      + bias_lds[tid]);
            const float gf = sigmoid_fast(g_lds[16 + tid] + bias_lds[16 + tid]);
            const float gc = tanh_fast   (g_lds[32 + tid] + bias_lds[32 + tid]);
            const float go = sigmoid_fast(g_lds[48 + tid] + bias_lds[48 + tid]);
            c_state = gf * c_state + gi * gc;
            const float h = go * tanh_fast(c_state);
            __hip_atomic_store(&hown[(t + 1) * HID + w * HCHUNK + tid], h,
                               __ATOMIC_RELAXED, __HIP_MEMORY_SCOPE_AGENT);
        }
        // release: own agent-scope (cache-bypassing) h stores complete, then flag.
        asm volatile("s_waitcnt vmcnt(0)" ::: "memory");
        __syncthreads();
        if (tid == 0) {
            __hip_atomic_store(&flags[wg], s + 1, __ATOMIC_RELAXED,
                               __HIP_MEMORY_SCOPE_AGENT);
        }
    }
}

// Head: out[t] = softmax( tanh(h2[t] @ W1^T + b1) @ W2^T + b2 )
__global__ void __launch_bounds__(256)
head_kernel(const float* __restrict__ ws_ro,
            const float* __restrict__ W1, const float* __restrict__ b1,
            const float* __restrict__ W2, const float* __restrict__ b2,
            float* __restrict__ out)
{
    __shared__ float w1_lds[26 * 516];   // padded stride to break bank conflicts
    __shared__ float b1_lds[26];
    __shared__ float w2_lds[52];
    __shared__ float g_lds[32];
    const int tid = threadIdx.x;

    for (int i = tid; i < 26 * 512; i += 256)
        w1_lds[(i >> 9) * 516 + (i & 511)] = W1[i];
    if (tid < 26) b1_lds[tid] = b1[tid];
    if (tid < 52) w2_lds[tid] = W2[tid];
    __syncthreads();

    const float* h2 = ws_ro + 128 + 2 * HSEQ_ELEMS;   // layer-2 h sequence base
    const int r = tid >> 3;   // 0..31 (rows 0..25 used)
    const int c = tid & 7;    // 8 chunks of 64

    for (int t = blockIdx.x; t < T_STEPS; t += HEAD_BLOCKS) {
        float acc = 0.0f;
        if (r < 26) {
            const float* hrow = h2 + (t + 1) * HID + c * 64;
            const float* wrow = &w1_lds[r * 516 + c * 64];
            #pragma unroll
            for (int k = 0; k < 64; k += 4) {
                const float4 hv = *reinterpret_cast<const float4*>(&hrow[k]);
                const float4 wv = *reinterpret_cast<const float4*>(&wrow[k]);
                acc += hv.x * wv.x + hv.y * wv.y + hv.z * wv.z + hv.w * wv.w;
            }
        }
        acc += __shfl_xor(acc, 1, 64);
        acc += __shfl_xor(acc, 2, 64);
        acc += __shfl_xor(acc, 4, 64);
        if (r < 26 && c == 0) g_lds[r] = acc;
        __syncthreads();
        if (tid == 0) {
            float l0 = b2[0], l1 = b2[1];
            for (int j = 0; j < 26; ++j) {
                const float tj = tanhf(g_lds[j] + b1_lds[j]);
                l0 = fmaf(w2_lds[j],      tj, l0);
                l1 = fmaf(w2_lds[26 + j], tj, l1);
            }
            const float m  = fmaxf(l0, l1);
            const float e0 = __expf(l0 - m), e1 = __expf(l1 - m);
            const float inv = 1.0f / (e0 + e1);
            out[t * 2 + 0] = e0 * inv;
            out[t * 2 + 1] = e1 * inv;
        }
        __syncthreads();
    }
}

extern "C" void kernel_launch(void* const* d_in, const int* in_sizes, int n_in,
                              void* d_out, int out_size, void* d_ws, size_t ws_size,
                              hipStream_t stream)
{
    const float* x    = (const float*)d_in[0];
    const float* Wih0 = (const float*)d_in[1];
    const float* Whh0 = (const float*)d_in[2];
    const float* bih0 = (const float*)d_in[3];
    const float* bhh0 = (const float*)d_in[4];
    const float* Wih1 = (const float*)d_in[5];
    const float* Whh1 = (const float*)d_in[6];
    const float* bih1 = (const float*)d_in[7];
    const float* bhh1 = (const float*)d_in[8];
    const float* Wih2 = (const float*)d_in[9];
    const float* Whh2 = (const float*)d_in[10];
    const float* bih2 = (const float*)d_in[11];
    const float* bhh2 = (const float*)d_in[12];
    const float* W1   = (const float*)d_in[13];
    const float* b1   = (const float*)d_in[14];
    const float* W2   = (const float*)d_in[15];
    const float* b2   = (const float*)d_in[16];

    float* ws = (float*)d_ws;

    // ws layout (floats): [0..128) flags ; then 3 x HSEQ_ELEMS h-sequences
    // (row 0 of each sequence = h_{-1} = 0). Total ~24 MB.
    hipMemsetAsync(d_ws, 0, 512, stream);                                              // flags
    hipMemsetAsync((char*)d_ws + 512, 0, HID * sizeof(float), stream);                 // h0 row0
    hipMemsetAsync((char*)d_ws + 512 + (size_t)HSEQ_ELEMS * 4, 0, HID * sizeof(float), stream);      // h1 row0
    hipMemsetAsync((char*)d_ws + 512 + (size_t)2 * HSEQ_ELEMS * 4, 0, HID * sizeof(float), stream);  // h2 row0

    lstm_scan<<<NWG, NTHREADS, 0, stream>>>(x,
        Wih0, Whh0, bih0, bhh0,
        Wih1, Whh1, bih1, bhh1,
        Wih2, Whh2, bih2, bhh2, ws);

    head_kernel<<<HEAD_BLOCKS, 256, 0, stream>>>(ws, W1, b1, W2, b2, (float*)d_out);
}

// Round 11
// 12275.642 us; speedup vs baseline: 8.9429x; 1.3132x over previous
//
#include <hip/hip_runtime.h>

#define T_STEPS 4096
#define HID 512
#define NLAYER 3
#define WGS_PER_LAYER 32
#define NWG (NLAYER * WGS_PER_LAYER)
#define NTHREADS 512
#define HCHUNK 16
#define S_TOTAL (T_STEPS + NLAYER - 1)
#define HSEQ_ELEMS ((T_STEPS + 1) * HID)
#define HEAD_BLOCKS 256

typedef float f32x16 __attribute__((ext_vector_type(16)));

__device__ __forceinline__ float sigmoid_fast(float x) {
    return 1.0f / (1.0f + __expf(-x));
}
__device__ __forceinline__ float tanh_fast(float x) {
    return 2.0f / (1.0f + __expf(-2.0f * x)) - 1.0f;
}
// XOR-swizzle on element index: spreads 128B-strided ds_read_b128 across banks (G4).
__device__ __forceinline__ int swz(int e) { return e ^ (((e >> 5) & 7) << 2); }

__device__ __forceinline__ float wload(int layer, const float* __restrict__ Wih,
                                       const float* __restrict__ Whh, int grow, int col) {
    if (col >= HID) return Whh[grow * HID + (col - HID)];
    if (layer == 0) return (col < 40) ? Wih[grow * 40 + col] : 0.0f;
    return Wih[grow * HID + col];
}

// Load 16 consecutive weight cols for local row r_, half h_ into named vector V.
#define LOADV(V, r_, h_) { \
    const int lr   = 4 * rg + (r_); \
    const int grow = ((lr >> 4) * HID) + w * HCHUNK + (lr & 15); \
    _Pragma("unroll") \
    for (int k = 0; k < 16; ++k) \
        V[k] = wload(layer, Wih, Whh, grow, cg * 32 + (h_) * 16 + k); }

#define STEP_J(jj, V0, V1, V2, V3, bb) { \
    const int e = (cg * 32 + (jj) * 4) ^ ((cg & 7) << 2); \
    const float4 hv4 = *reinterpret_cast<const float4*>(&v_lds[e]); \
    acc0 = fmaf(V0[(bb)+0], hv4.x, acc0); \
    acc0 = fmaf(V0[(bb)+1], hv4.y, acc0); \
    acc0 = fmaf(V0[(bb)+2], hv4.z, acc0); \
    acc0 = fmaf(V0[(bb)+3], hv4.w, acc0); \
    acc1 = fmaf(V1[(bb)+0], hv4.x, acc1); \
    acc1 = fmaf(V1[(bb)+1], hv4.y, acc1); \
    acc1 = fmaf(V1[(bb)+2], hv4.z, acc1); \
    acc1 = fmaf(V1[(bb)+3], hv4.w, acc1); \
    acc2 = fmaf(V2[(bb)+0], hv4.x, acc2); \
    acc2 = fmaf(V2[(bb)+1], hv4.y, acc2); \
    acc2 = fmaf(V2[(bb)+2], hv4.z, acc2); \
    acc2 = fmaf(V2[(bb)+3], hv4.w, acc2); \
    acc3 = fmaf(V3[(bb)+0], hv4.x, acc3); \
    acc3 = fmaf(V3[(bb)+1], hv4.y, acc3); \
    acc3 = fmaf(V3[(bb)+2], hv4.z, acc3); \
    acc3 = fmaf(V3[(bb)+3], hv4.w, acc3); }

// Persistent systolic 3-layer LSTM scan. 96 WGs: WG = layer*32 + w.
// Layer l at global step s computes timestep t = s - l.
// Weights stationary in VGPRs (128/thread, pinned via opaque asm against remat).
__global__ void __launch_bounds__(NTHREADS, 1)
lstm_scan(const float* __restrict__ x,
          const float* __restrict__ Wih0, const float* __restrict__ Whh0,
          const float* __restrict__ bih0, const float* __restrict__ bhh0,
          const float* __restrict__ Wih1, const float* __restrict__ Whh1,
          const float* __restrict__ bih1, const float* __restrict__ bhh1,
          const float* __restrict__ Wih2, const float* __restrict__ Whh2,
          const float* __restrict__ bih2, const float* __restrict__ bhh2,
          float* __restrict__ ws)
{
    const int wg    = blockIdx.x;
    const int layer = wg >> 5;
    const int w     = wg & 31;
    const int tid   = threadIdx.x;
    const int rg    = tid >> 5;   // row-group 0..15 (4 rows each)
    const int cg    = tid & 31;   // col-group 0..31 (32 cols each)

    int*   flags = (int*)ws;
    float* hseq0 = ws + 128;
    float* hseq1 = hseq0 + HSEQ_ELEMS;
    float* hseq2 = hseq1 + HSEQ_ELEMS;
    float* hown        = (layer == 0) ? hseq0 : ((layer == 1) ? hseq1 : hseq2);
    const float* hprev = (layer == 0) ? hseq0 : ((layer == 1) ? hseq0 : hseq1);

    const float* Wih = (layer == 0) ? Wih0 : ((layer == 1) ? Wih1 : Wih2);
    const float* Whh = (layer == 0) ? Whh0 : ((layer == 1) ? Whh1 : Whh2);
    const float* bih = (layer == 0) ? bih0 : ((layer == 1) ? bih1 : bih2);
    const float* bhh = (layer == 0) ? bhh0 : ((layer == 1) ? bhh1 : bhh2);

    __shared__ float v_lds[1024];
    __shared__ float g_lds[64];
    __shared__ float bias_lds[64];

    // ---- stationary weights: 4 rows x 32 cols per thread, in named vector regs ----
    f32x16 wv0, wv1, wv2, wv3, wv4, wv5, wv6, wv7;
    LOADV(wv0, 0, 0) LOADV(wv1, 0, 1)
    LOADV(wv2, 1, 0) LOADV(wv3, 1, 1)
    LOADV(wv4, 2, 0) LOADV(wv5, 2, 1)
    LOADV(wv6, 3, 0) LOADV(wv7, 3, 1)

    if (tid < 64) {
        const int lr   = tid;
        const int grow = ((lr >> 4) * HID) + w * HCHUNK + (lr & 15);
        bias_lds[lr] = bih[grow] + bhh[grow];
    }

    float c_state = 0.0f;   // cell state, meaningful for tid < 16

    for (int s = 0; s < S_TOTAL; ++s) {
        const int  t      = s - layer;
        const bool active = (t >= 0) && (t < T_STEPS);

        // Pin the weight vectors: opaque redefinition makes them loop-carried asm
        // outputs -> the compiler cannot rematerialize the global loads inside the
        // loop; 128 floats/thread stay VGPR-resident. Emits zero instructions.
        asm volatile("" : "+v"(wv0), "+v"(wv1), "+v"(wv2), "+v"(wv3),
                          "+v"(wv4), "+v"(wv5), "+v"(wv6), "+v"(wv7));

        // ---- wait: layers {l-1, l} must have finished step s-1 (64 flags) ----
        if (s > 0) {
            if (tid < 64) {
                const int fidx = (layer == 0) ? (tid & 31) : ((layer - 1) * 32 + tid);
                while (1) {
                    const int f = __hip_atomic_load(&flags[fidx], __ATOMIC_RELAXED,
                                                    __HIP_MEMORY_SCOPE_AGENT);
                    if (__all(f >= s)) break;
                }
            }
            asm volatile("" ::: "memory");   // compiler barrier: no load hoisting above poll
        }
        __syncthreads();

        // ---- stage v = [x_part | h_prev] into LDS (swizzled) ----
        if (active) {
            float xv, hv;
            if (layer == 0) {
                xv = (tid < 40) ? x[t * 40 + tid] : 0.0f;
            } else {
                xv = __hip_atomic_load(&hprev[(t + 1) * HID + tid], __ATOMIC_RELAXED,
                                       __HIP_MEMORY_SCOPE_AGENT);
            }
            hv = __hip_atomic_load(&hown[t * HID + tid], __ATOMIC_RELAXED,
                                   __HIP_MEMORY_SCOPE_AGENT);
            v_lds[swz(tid)]       = xv;
            v_lds[swz(HID + tid)] = hv;
        }
        __syncthreads();

        // ---- matvec: 4 rows x 32 cols from registers ----
        if (active) {
            float acc0 = 0.f, acc1 = 0.f, acc2 = 0.f, acc3 = 0.f;
            STEP_J(0, wv0, wv2, wv4, wv6, 0)
            STEP_J(1, wv0, wv2, wv4, wv6, 4)
            STEP_J(2, wv0, wv2, wv4, wv6, 8)
            STEP_J(3, wv0, wv2, wv4, wv6, 12)
            STEP_J(4, wv1, wv3, wv5, wv7, 0)
            STEP_J(5, wv1, wv3, wv5, wv7, 4)
            STEP_J(6, wv1, wv3, wv5, wv7, 8)
            STEP_J(7, wv1, wv3, wv5, wv7, 12)
            #pragma unroll
            for (int m = 1; m < 32; m <<= 1) {
                acc0 += __shfl_xor(acc0, m, 64);
                acc1 += __shfl_xor(acc1, m, 64);
                acc2 += __shfl_xor(acc2, m, 64);
                acc3 += __shfl_xor(acc3, m, 64);
            }
            if (cg == 0) {
                g_lds[4 * rg + 0] = acc0;
                g_lds[4 * rg + 1] = acc1;
                g_lds[4 * rg + 2] = acc2;
                g_lds[4 * rg + 3] = acc3;
            }
        }
        __syncthreads();

        // ---- gates, state update, publish h chunk ----
        if (active && tid < HCHUNK) {
            const float gi = sigmoid_fast(g_lds[tid]      + bias_lds[tid]);
            const float gf = sigmoid_fast(g_lds[16 + tid] + bias_lds[16 + tid]);
            const float gc = tanh_fast   (g_lds[32 + tid] + bias_lds[32 + tid]);
            const float go = sigmoid_fast(g_lds[48 + tid] + bias_lds[48 + tid]);
            c_state = gf * c_state + gi * gc;
            const float h = go * tanh_fast(c_state);
            __hip_atomic_store(&hown[(t + 1) * HID + w * HCHUNK + tid], h,
                               __ATOMIC_RELAXED, __HIP_MEMORY_SCOPE_AGENT);
        }
        // release: own agent-scope (cache-bypassing) h stores complete, then flag.
        asm volatile("s_waitcnt vmcnt(0)" ::: "memory");
        __syncthreads();
        if (tid == 0) {
            __hip_atomic_store(&flags[wg], s + 1, __ATOMIC_RELAXED,
                               __HIP_MEMORY_SCOPE_AGENT);
        }
    }
}

// Head: out[t] = softmax( tanh(h2[t] @ W1^T + b1) @ W2^T + b2 )
__global__ void __launch_bounds__(256)
head_kernel(const float* __restrict__ ws_ro,
            const float* __restrict__ W1, const float* __restrict__ b1,
            const float* __restrict__ W2, const float* __restrict__ b2,
            float* __restrict__ out)
{
    __shared__ float w1_lds[26 * 516];   // padded stride to break bank conflicts
    __shared__ float b1_lds[26];
    __shared__ float w2_lds[52];
    __shared__ float g_lds[32];
    const int tid = threadIdx.x;

    for (int i = tid; i < 26 * 512; i += 256)
        w1_lds[(i >> 9) * 516 + (i & 511)] = W1[i];
    if (tid < 26) b1_lds[tid] = b1[tid];
    if (tid < 52) w2_lds[tid] = W2[tid];
    __syncthreads();

    const float* h2 = ws_ro + 128 + 2 * HSEQ_ELEMS;   // layer-2 h sequence base
    const int r = tid >> 3;   // 0..31 (rows 0..25 used)
    const int c = tid & 7;    // 8 chunks of 64

    for (int t = blockIdx.x; t < T_STEPS; t += HEAD_BLOCKS) {
        float acc = 0.0f;
        if (r < 26) {
            const float* hrow = h2 + (t + 1) * HID + c * 64;
            const float* wrow = &w1_lds[r * 516 + c * 64];
            #pragma unroll
            for (int k = 0; k < 64; k += 4) {
                const float4 hv = *reinterpret_cast<const float4*>(&hrow[k]);
                const float4 wv = *reinterpret_cast<const float4*>(&wrow[k]);
                acc += hv.x * wv.x + hv.y * wv.y + hv.z * wv.z + hv.w * wv.w;
            }
        }
        acc += __shfl_xor(acc, 1, 64);
        acc += __shfl_xor(acc, 2, 64);
        acc += __shfl_xor(acc, 4, 64);
        if (r < 26 && c == 0) g_lds[r] = acc;
        __syncthreads();
        if (tid == 0) {
            float l0 = b2[0], l1 = b2[1];
            for (int j = 0; j < 26; ++j) {
                const float tj = tanhf(g_lds[j] + b1_lds[j]);
                l0 = fmaf(w2_lds[j],      tj, l0);
                l1 = fmaf(w2_lds[26 + j], tj, l1);
            }
            const float m  = fmaxf(l0, l1);
            const float e0 = __expf(l0 - m), e1 = __expf(l1 - m);
            const float inv = 1.0f / (e0 + e1);
            out[t * 2 + 0] = e0 * inv;
            out[t * 2 + 1] = e1 * inv;
        }
        __syncthreads();
    }
}

extern "C" void kernel_launch(void* const* d_in, const int* in_sizes, int n_in,
                              void* d_out, int out_size, void* d_ws, size_t ws_size,
                              hipStream_t stream)
{
    const float* x    = (const float*)d_in[0];
    const float* Wih0 = (const float*)d_in[1];
    const float* Whh0 = (const float*)d_in[2];
    const float* bih0 = (const float*)d_in[3];
    const float* bhh0 = (const float*)d_in[4];
    const float* Wih1 = (const float*)d_in[5];
    const float* Whh1 = (const float*)d_in[6];
    const float* bih1 = (const float*)d_in[7];
    const float* bhh1 = (const float*)d_in[8];
    const float* Wih2 = (const float*)d_in[9];
    const float* Whh2 = (const float*)d_in[10];
    const float* bih2 = (const float*)d_in[11];
    const float* bhh2 = (const float*)d_in[12];
    const float* W1   = (const float*)d_in[13];
    const float* b1   = (const float*)d_in[14];
    const float* W2   = (const float*)d_in[15];
    const float* b2   = (const float*)d_in[16];

    float* ws = (float*)d_ws;

    // ws layout (floats): [0..128) flags ; then 3 x HSEQ_ELEMS h-sequences
    // (row 0 of each sequence = h_{-1} = 0). Total ~24 MB.
    hipMemsetAsync(d_ws, 0, 512, stream);                                              // flags
    hipMemsetAsync((char*)d_ws + 512, 0, HID * sizeof(float), stream);                 // h0 row0
    hipMemsetAsync((char*)d_ws + 512 + (size_t)HSEQ_ELEMS * 4, 0, HID * sizeof(float), stream);      // h1 row0
    hipMemsetAsync((char*)d_ws + 512 + (size_t)2 * HSEQ_ELEMS * 4, 0, HID * sizeof(float), stream);  // h2 row0

    lstm_scan<<<NWG, NTHREADS, 0, stream>>>(x,
        Wih0, Whh0, bih0, bhh0,
        Wih1, Whh1, bih1, bhh1,
        Wih2, Whh2, bih2, bhh2, ws);

    head_kernel<<<HEAD_BLOCKS, 256, 0, stream>>>(ws, W1, b1, W2, b2, (float*)d_out);
}